// Round 11
// baseline (205.817 us; speedup 1.0000x reference)
//
#include <hip/hip_runtime.h>
#include <stdint.h>

#define M_DIM 8192
#define K_DIM 4096
#define N_DIM 4096

#define BM 256
#define BN 256
#define BKB 128   // K-bytes (=elements) per tile, i8
#define NTILES 32 // K_DIM / BKB
#define NITER 16  // NTILES / 2

typedef __attribute__((ext_vector_type(4))) int i32x4;
typedef unsigned char u8;
typedef unsigned int u32;

// ---------------- prepass: quantize x to per-row i8, w to sign i8 ----------------

__device__ __forceinline__ signed char sgn8(float f) {
  return (f > 0.0f) ? (signed char)1 : ((f < 0.0f) ? (signed char)-1 : (signed char)0);
}

// one block per row: rowmax -> scale -> quantize 4096 floats to i8
__global__ __launch_bounds__(256) void cvt_x_i8(const float* __restrict__ x,
                                                signed char* __restrict__ xq,
                                                float* __restrict__ scales) {
  const int row = blockIdx.x;
  const float4* xr = (const float4*)(x + (size_t)row * K_DIM);
  const int tid = threadIdx.x;

  float4 v[4];
#pragma unroll
  for (int k = 0; k < 4; ++k) v[k] = xr[tid * 4 + k];

  float m = 0.0f;
#pragma unroll
  for (int k = 0; k < 4; ++k) {
    m = fmaxf(m, fmaxf(fmaxf(fabsf(v[k].x), fabsf(v[k].y)),
                       fmaxf(fabsf(v[k].z), fabsf(v[k].w))));
  }
#pragma unroll
  for (int off = 32; off; off >>= 1) m = fmaxf(m, __shfl_xor(m, off));

  __shared__ float wmax[4];
  if ((tid & 63) == 0) wmax[tid >> 6] = m;
  __syncthreads();
  m = fmaxf(fmaxf(wmax[0], wmax[1]), fmaxf(wmax[2], wmax[3]));
  m = fmaxf(m, 1e-30f);

  const float inv = 127.0f / m;
  if (tid == 0) scales[row] = m / 127.0f;

  signed char q[16] __attribute__((aligned(16)));
#pragma unroll
  for (int k = 0; k < 4; ++k) {
    const float* p = (const float*)&v[k];
#pragma unroll
    for (int j = 0; j < 4; ++j) {
      float t = fminf(fmaxf(p[j] * inv, -127.0f), 127.0f);
      q[k * 4 + j] = (signed char)__float2int_rn(t);
    }
  }
  *(int4*)(xq + (size_t)row * K_DIM + tid * 16) = *(const int4*)q;
}

__global__ __launch_bounds__(256) void cvt_w_i8(const float4* __restrict__ w,
                                                int4* __restrict__ wq) {
  const int i = blockIdx.x * blockDim.x + threadIdx.x;  // 16 floats / thread
  signed char q[16] __attribute__((aligned(16)));
#pragma unroll
  for (int k = 0; k < 4; ++k) {
    float4 v = w[i * 4 + k];
    q[k * 4 + 0] = sgn8(v.x);
    q[k * 4 + 1] = sgn8(v.y);
    q[k * 4 + 2] = sgn8(v.z);
    q[k * 4 + 3] = sgn8(v.w);
  }
  wq[i] = *(const int4*)q;
}

// ---------------- GEMM ----------------

// async global->LDS, 16 B/lane. LDS dest is the WAVE-UNIFORM base (HW adds lane*16);
// global src is per-lane (pre-swizzled so the linear LDS write lands swizzled).
__device__ __forceinline__ void load16_to_lds(const u8* g, const u8* l) {
  auto gp = reinterpret_cast<const __attribute__((address_space(1))) void*>(
      reinterpret_cast<uintptr_t>(g));
  auto lp = reinterpret_cast<__attribute__((address_space(3))) void*>(
      static_cast<uint32_t>(reinterpret_cast<uintptr_t>(l)));
  __builtin_amdgcn_global_load_lds(gp, lp, 16, 0, 0);
}

__device__ __forceinline__ i32x4 lds_read(const u8* base, int byteoff) {
  return *(const i32x4*)(base + byteoff);
}

// 256x256 i8 GEMM, 4-WAVE FAT TILING: C = s_row * (Xq * Wq^T).
// Rounds 3-10: per-tile time == LDS-port floor (2304cyc: 192 ds_read_b128)
// + MFMA floor (2341cyc), i.e. zero overlap, MfmaUtil pinned at 43% across
// FIVE schedules. Invariant cause: 8-wave (128x64) tiling re-reads each
// staged byte 3x. Fix: 4 waves (one per SIMD), each computing 128x128 ->
// Sum(M_w+N_w) drops 1536->1024 -> port floor 1536 cyc. acc[8][8]=256 VGPR
// + frags 64 legal at 1 wave/SIMD (512-reg budget, launch_bounds(256,1)).
// Port/MFMA overlap now comes from in-wave ILP (32 indep reads + 128 MFMAs,
// compiler-scheduled, no manual intra-tile waits). Tile-gate ledger = round 6:
// depth-1 dbuf, reads(t)/stages(t+1) disjoint buffers, vmcnt(0)+barrier gate.
// Staging: 4 regions of 16KB; wave covers rows {g*32+wave*8+l3, g=0..3} of
// each region; csw identity (l7^l3) unchanged since wave*8 % 8 == 0.

#define STAGE_REGION(bufp, gptr, T)                                         \
  do {                                                                      \
    const u8* _s = (gptr) + (size_t)(T) * BKB;                              \
    _Pragma("unroll") for (int g = 0; g < 4; ++g)                           \
        load16_to_lds(_s + (size_t)(g * 32) * K_DIM,                        \
                      (bufp) + g * 4096 + ldsw);                            \
  } while (0)

#define STAGE_TILE(buf, T)                                                  \
  do {                                                                      \
    STAGE_REGION(&lds[buf][0][0][0], gA0, T);                               \
    STAGE_REGION(&lds[buf][0][1][0], gA1, T);                               \
    STAGE_REGION(&lds[buf][1][0][0], gB0, T);                               \
    STAGE_REGION(&lds[buf][1][1][0], gB1, T);                               \
  } while (0)

// All 32 reads + 128 MFMAs of one tile; reads interleaved so early MFMAs'
// operands return first; all indices compile-time constant (rule #20).
#define COMPUTE_TILE(buf)                                                   \
  do {                                                                      \
    _Pragma("unroll") for (int r = 0; r < 8; ++r) {                         \
      _Pragma("unroll") for (int kk = 0; kk < 2; ++kk) {                    \
        af[r][kk] = lds_read(Ab[buf], r * 2048 + rowb + ck[kk]);            \
        bf[r][kk] = lds_read(Bb[buf], r * 2048 + rowb + ck[kk]);            \
      }                                                                     \
    }                                                                       \
    _Pragma("unroll") for (int mi = 0; mi < 8; ++mi)                        \
    _Pragma("unroll") for (int ni = 0; ni < 8; ++ni)                        \
    _Pragma("unroll") for (int kk = 0; kk < 2; ++kk)                        \
        acc[mi][ni] = __builtin_amdgcn_mfma_i32_16x16x64_i8(                \
            af[mi][kk], bf[ni][kk], acc[mi][ni], 0, 0, 0);                  \
  } while (0)

#define TILE_GATE()                                      \
  asm volatile("s_waitcnt vmcnt(0)" ::: "memory");       \
  __builtin_amdgcn_s_barrier()

__global__ __launch_bounds__(256, 1) void bingemm_kernel(const u8* __restrict__ A,
                                                         const u8* __restrict__ B,
                                                         const float* __restrict__ S,
                                                         float* __restrict__ C) {
  __shared__ __align__(16) u8 lds[2][2][2][16384];  // 128 KiB

  const int tid = threadIdx.x;
  const int wave = tid >> 6;  // 0..3, one per SIMD
  const int lane = tid & 63;

  // XCD-bijective swizzle (512 blocks % 8 XCDs == 0)
  const int orig = blockIdx.x;
  const int wgid = (orig & 7) * 64 + (orig >> 3);
  const int bm = wgid >> 4;  // 0..31
  const int bn = wgid & 15;  // 0..15

  const int wm = wave >> 1;  // wave's 128-row half
  const int wn = wave & 1;   // wave's 128-col half

  // ---- staging addresses (per-lane global src, pre-swizzled 16B chunk) ----
  const int l3 = lane >> 3;
  const int l7 = lane & 7;
  const int csw = (l7 ^ l3) << 4;  // swizzled chunk -> byte offset in 128B row
  const u8* gA0 = A + (size_t)(bm * 256 + wave * 8 + l3) * K_DIM + csw;
  const u8* gA1 = gA0 + (size_t)128 * K_DIM;
  const u8* gB0 = B + (size_t)(bn * 256 + wave * 8 + l3) * K_DIM + csw;
  const u8* gB1 = gB0 + (size_t)128 * K_DIM;
  const int ldsw = wave * 1024;  // wave-uniform byte offset within a 4KB group

  // ---- ds_read fragment addressing (swizzled) ----
  const int lane15 = lane & 15;
  const int lgrp = lane >> 4;
  const int rowb = lane15 * 128;  // byte row offset; row&7 == lane&7 for frag rows
  const int ck[2] = {((lgrp ^ l7) << 4), (((4 + lgrp) ^ l7) << 4)};
  const u8* Ab[2] = {&lds[0][0][wm][0], &lds[1][0][wm][0]};
  const u8* Bb[2] = {&lds[0][1][wn][0], &lds[1][1][wn][0]};

  i32x4 acc[8][8];
  {
    const i32x4 z = {0, 0, 0, 0};
#pragma unroll
    for (int i = 0; i < 8; ++i)
#pragma unroll
      for (int j = 0; j < 8; ++j) acc[i][j] = z;
  }
  i32x4 af[8][2], bf[8][2];

  // ---- prologue: stage tile 0 into buf0, drain, sync ----
  STAGE_TILE(0, 0);
  TILE_GATE();

  for (int i = 0; i < NITER; ++i) {
    const int T1 = 2 * i + 1, T2 = 2 * i + 2;

    // ---- tile T0 = 2i (buf0); prefetch T1 -> buf1 ----
    STAGE_TILE(1, T1);
    COMPUTE_TILE(0);
    TILE_GATE();

    // ---- tile T1 (buf1); prefetch T2 -> buf0 ----
    if (i < NITER - 1) STAGE_TILE(0, T2);
    COMPUTE_TILE(1);
    TILE_GATE();
  }

  // ---- epilogue: C/D layout col=lane&15, row=(lane>>4)*4+reg; dequant ----
  const int ccol = bn * 256 + wn * 128 + lane15;
  const int crow0 = bm * 256 + wm * 128 + (lgrp << 2);
#pragma unroll
  for (int mi = 0; mi < 8; ++mi) {
#pragma unroll
    for (int j = 0; j < 4; ++j) {
      const int row = crow0 + mi * 16 + j;
      const float s = S[row];
      float* cp = C + (size_t)row * N_DIM + ccol;
#pragma unroll
      for (int ni = 0; ni < 8; ++ni) cp[ni * 16] = s * (float)acc[mi][ni][j];
    }
  }
}

// Correctness fallback if d_ws is too small for the i8 staging buffers.
__global__ __launch_bounds__(256) void fallback_kernel(const float* __restrict__ x,
                                                       const float* __restrict__ w,
                                                       float* __restrict__ out) {
  const int col = blockIdx.x * 256 + threadIdx.x;
  const int row = blockIdx.y;
  const float* xr = x + (size_t)row * K_DIM;
  const float* wr = w + (size_t)col * K_DIM;
  float acc = 0.0f;
  for (int k = 0; k < K_DIM; k += 4) {
    float4 xv = *(const float4*)&xr[k];
    float4 wv = *(const float4*)&wr[k];
    acc += (wv.x > 0.0f ? xv.x : (wv.x < 0.0f ? -xv.x : 0.0f));
    acc += (wv.y > 0.0f ? xv.y : (wv.y < 0.0f ? -xv.y : 0.0f));
    acc += (wv.z > 0.0f ? xv.z : (wv.z < 0.0f ? -xv.z : 0.0f));
    acc += (wv.w > 0.0f ? xv.w : (wv.w < 0.0f ? -xv.w : 0.0f));
  }
  out[(size_t)row * N_DIM + col] = acc;
}

extern "C" void kernel_launch(void* const* d_in, const int* in_sizes, int n_in,
                              void* d_out, int out_size, void* d_ws, size_t ws_size,
                              hipStream_t stream) {
  const float* x = (const float*)d_in[0];  // (8192, 4096) fp32
  const float* w = (const float*)d_in[1];  // (4096, 4096) fp32
  float* out = (float*)d_out;              // (8192, 4096) fp32

  const size_t x_elems = (size_t)M_DIM * K_DIM;
  const size_t w_elems = (size_t)N_DIM * K_DIM;
  const size_t need = x_elems + w_elems + (size_t)M_DIM * sizeof(float);

  if (ws_size < need) {
    dim3 fgrid(N_DIM / 256, M_DIM);
    fallback_kernel<<<fgrid, 256, 0, stream>>>(x, w, out);
    return;
  }

  signed char* xq = (signed char*)d_ws;    // 32 MiB
  signed char* wq = xq + x_elems;          // 16 MiB
  float* scales = (float*)(wq + w_elems);  // 32 KiB

  cvt_x_i8<<<M_DIM, 256, 0, stream>>>(x, xq, scales);
  cvt_w_i8<<<(int)(w_elems / 16 / 256), 256, 0, stream>>>((const float4*)w, (int4*)wq);

  bingemm_kernel<<<(M_DIM / BM) * (N_DIM / BN), 256, 0, stream>>>(
      (const u8*)xq, (const u8*)wq, scales, out);
}

// Round 12
// 191.506 us; speedup vs baseline: 1.0747x; 1.0747x over previous
//
#include <hip/hip_runtime.h>
#include <stdint.h>

#define M_DIM 8192
#define K_DIM 4096
#define N_DIM 4096

#define BM 256
#define BN 256
#define BKB 128   // K-bytes (=elements) per tile, i8
#define NTILES 32 // K_DIM / BKB
#define NITER 16  // NTILES / 2

typedef __attribute__((ext_vector_type(4))) int i32x4;
typedef unsigned char u8;
typedef unsigned int u32;

// ---------------- prepass ----------------

__device__ __forceinline__ signed char sgn8(float f) {
  return (f > 0.0f) ? (signed char)1 : ((f < 0.0f) ? (signed char)-1 : (signed char)0);
}

// one block per row: rowmax -> scale -> quantize 4096 floats to i8
__global__ __launch_bounds__(256) void cvt_x_i8(const float* __restrict__ x,
                                                signed char* __restrict__ xq,
                                                float* __restrict__ scales) {
  const int row = blockIdx.x;
  const float4* xr = (const float4*)(x + (size_t)row * K_DIM);
  const int tid = threadIdx.x;

  float4 v[4];
#pragma unroll
  for (int k = 0; k < 4; ++k) v[k] = xr[tid * 4 + k];

  float m = 0.0f;
#pragma unroll
  for (int k = 0; k < 4; ++k) {
    m = fmaxf(m, fmaxf(fmaxf(fabsf(v[k].x), fabsf(v[k].y)),
                       fmaxf(fabsf(v[k].z), fabsf(v[k].w))));
  }
#pragma unroll
  for (int off = 32; off; off >>= 1) m = fmaxf(m, __shfl_xor(m, off));

  __shared__ float wmax[4];
  if ((tid & 63) == 0) wmax[tid >> 6] = m;
  __syncthreads();
  m = fmaxf(fmaxf(wmax[0], wmax[1]), fmaxf(wmax[2], wmax[3]));
  m = fmaxf(m, 1e-30f);

  const float inv = 127.0f / m;
  if (tid == 0) scales[row] = m / 127.0f;

  signed char q[16] __attribute__((aligned(16)));
#pragma unroll
  for (int k = 0; k < 4; ++k) {
    const float* p = (const float*)&v[k];
#pragma unroll
    for (int j = 0; j < 4; ++j) {
      float t = fminf(fmaxf(p[j] * inv, -127.0f), 127.0f);
      q[k * 4 + j] = (signed char)__float2int_rn(t);
    }
  }
  *(int4*)(xq + (size_t)row * K_DIM + tid * 16) = *(const int4*)q;
}

// W -> sign-i8 in FRAGMENT-TILED layout:
//   wq_t[g][kc][r][0..15] at byte g*65536 + kc*256 + r*16,
//   where o = g*16 + r (output col), k = kc*16 + (0..15).
// A wave's B-fragment load (ni,kk) is then lane-contiguous 1KB:
//   lane = r + 16*lgrp -> addr = base(g) + (T*8+kk*4+lgrp)*256 + r*16.
// Block b: g = b>>4, kco = b&15; thread t: r = t>>4, kcl = t&15.
__global__ __launch_bounds__(256) void cvt_w_i8t(const float* __restrict__ w,
                                                 signed char* __restrict__ wq) {
  const int b = blockIdx.x;
  const int g = b >> 4, kco = b & 15;
  const int t = threadIdx.x;
  const int r = t >> 4, kcl = t & 15;
  const int kc = kco * 16 + kcl;

  const float4* src = (const float4*)(w + (size_t)(g * 16 + r) * K_DIM + kc * 16);
  signed char q[16] __attribute__((aligned(16)));
#pragma unroll
  for (int k = 0; k < 4; ++k) {
    float4 v = src[k];
    q[k * 4 + 0] = sgn8(v.x);
    q[k * 4 + 1] = sgn8(v.y);
    q[k * 4 + 2] = sgn8(v.z);
    q[k * 4 + 3] = sgn8(v.w);
  }
  *(int4*)(wq + (size_t)g * 65536 + kc * 256 + r * 16) = *(const int4*)q;
}

// ---------------- GEMM ----------------

// async global->LDS, 16 B/lane. LDS dest is the WAVE-UNIFORM base (HW adds lane*16);
// global src is per-lane (pre-swizzled so the linear LDS write lands swizzled).
__device__ __forceinline__ void load16_to_lds(const u8* g, const u8* l) {
  auto gp = reinterpret_cast<const __attribute__((address_space(1))) void*>(
      reinterpret_cast<uintptr_t>(g));
  auto lp = reinterpret_cast<__attribute__((address_space(3))) void*>(
      static_cast<uint32_t>(reinterpret_cast<uintptr_t>(l)));
  __builtin_amdgcn_global_load_lds(gp, lp, 16, 0, 0);
}

__device__ __forceinline__ i32x4 lds_read(const u8* base, int byteoff) {
  return *(const i32x4*)(base + byteoff);
}

// 256x256 i8 GEMM, B DIRECT-FROM-GLOBAL (fragment-tiled wq_t), A in LDS.
// Rounds 3-10 invariant: per-tile = LDS-port floor + MFMA floor (additive,
// MfmaUtil 43% across 6 schedules). This round REMOVES the B half of the
// port floor: B frags stream from L2 via perfectly-coalesced 1KB
// global_load_dwordx4 into a tile-ahead register double-buffer (bfA/bfB,
// statically named per rule #20); LDS keeps A only (64 KiB, 128 reads/tile
// vs 192). Tile gate (vmcnt(0)+s_barrier) drains A-staging AND next-tile B
// loads -> B latency fully hidden under the current tile's compute, no new
// sync. A hazard ledger identical to round 6. No manual intra-tile waits
// (m141). XCD swizzle regrouped so same-XCD blocks share bn (B slice 2MB
// L2-resident; A panels via L3).

#define STAGE_A(buf, T)                                                     \
  do {                                                                      \
    _Pragma("unroll") for (int half = 0; half < 2; ++half) {                \
      const u8* _s = gAh[half] + (size_t)(T) * BKB;                         \
      const u8* _r = &lds[buf][half][0] + ldsw;                             \
      load16_to_lds(_s, _r);                                                \
      load16_to_lds(_s + (size_t)64 * K_DIM, _r + 8192);                    \
    }                                                                       \
  } while (0)

#define LOADB(dst, T)                                                       \
  _Pragma("unroll") for (int ni = 0; ni < 4; ++ni)                          \
  _Pragma("unroll") for (int kk = 0; kk < 2; ++kk)                          \
      dst[ni][kk] = *(const i32x4*)(gBf[ni] + (size_t)(T) * 2048 + kk * 1024)

// 16 A ds_reads + 64 MFMAs; af halved (mi 0-3 then 4-7) to cap registers.
#define COMPUTE(buf, bf)                                                    \
  do {                                                                      \
    _Pragma("unroll") for (int mi = 0; mi < 4; ++mi)                        \
    _Pragma("unroll") for (int kk = 0; kk < 2; ++kk)                        \
        af[mi][kk] = lds_read(Ab[buf], mi * 2048 + rowb + ck[kk]);          \
    _Pragma("unroll") for (int mi = 0; mi < 4; ++mi)                        \
    _Pragma("unroll") for (int ni = 0; ni < 4; ++ni)                        \
    _Pragma("unroll") for (int kk = 0; kk < 2; ++kk)                        \
        acc[mi][ni] = __builtin_amdgcn_mfma_i32_16x16x64_i8(                \
            af[mi][kk], bf[ni][kk], acc[mi][ni], 0, 0, 0);                  \
    _Pragma("unroll") for (int mi = 0; mi < 4; ++mi)                        \
    _Pragma("unroll") for (int kk = 0; kk < 2; ++kk)                        \
        af[mi][kk] = lds_read(Ab[buf], (4 + mi) * 2048 + rowb + ck[kk]);    \
    _Pragma("unroll") for (int mi = 0; mi < 4; ++mi)                        \
    _Pragma("unroll") for (int ni = 0; ni < 4; ++ni)                        \
    _Pragma("unroll") for (int kk = 0; kk < 2; ++kk)                        \
        acc[4 + mi][ni] = __builtin_amdgcn_mfma_i32_16x16x64_i8(            \
            af[mi][kk], bf[ni][kk], acc[4 + mi][ni], 0, 0, 0);              \
  } while (0)

#define TILE_GATE()                                      \
  asm volatile("s_waitcnt vmcnt(0)" ::: "memory");       \
  __builtin_amdgcn_s_barrier()

__global__ __launch_bounds__(512, 2) void bingemm_kernel(const u8* __restrict__ A,
                                                         const u8* __restrict__ Bt,
                                                         const float* __restrict__ S,
                                                         float* __restrict__ C) {
  __shared__ __align__(16) u8 lds[2][2][16384];  // 64 KiB, A only

  const int tid = threadIdx.x;
  const int wave = tid >> 6;
  const int lane = tid & 63;

  // XCD swizzle: same-XCD blocks share a 2-wide bn slice (B 2MB -> L2-resident),
  // sweep all bm (A via L3). Bijective over 512 blocks (xcd 0-7, j 0-63).
  const int orig = blockIdx.x;
  const int xcd = orig & 7;
  const int j = orig >> 3;
  const int bn = xcd * 2 + (j >> 5);  // 0..15
  const int bm = j & 31;              // 0..31

  const int wm = wave >> 2;  // wave's A half (128 rows)
  const int wn = wave & 3;   // wave's 64-col slice

  // ---- A staging addresses (per-lane global src, pre-swizzled 16B chunk) ----
  const int l3 = lane >> 3;
  const int l7 = lane & 7;
  const int csw = (l7 ^ l3) << 4;  // swizzled chunk -> byte offset in 128B row
  const u8* gA = A + (size_t)(bm * 256 + wave * 8 + l3) * K_DIM + csw;
  const u8* gAh[2] = {gA, gA + (size_t)128 * K_DIM};
  const int ldsw = wave * 1024;  // wave-uniform byte offset within a region issue

  // ---- A ds_read fragment addressing (swizzled) ----
  const int lane15 = lane & 15;
  const int lgrp = lane >> 4;
  const int rowb = lane15 * 128;
  const int ck[2] = {((lgrp ^ l7) << 4), (((4 + lgrp) ^ l7) << 4)};
  const u8* Ab[2] = {&lds[0][wm][0], &lds[1][wm][0]};

  // ---- B fragment bases (fragment-tiled layout, 1KB/load coalesced) ----
  // frag(ni,kk) lane addr = (bn*16+wn*4+ni)*65536 + (T*8+kk*4+lgrp)*256 + lane15*16
  const u8* gBf[4];
#pragma unroll
  for (int ni = 0; ni < 4; ++ni)
    gBf[ni] = Bt + (size_t)(bn * 16 + wn * 4 + ni) * 65536 + lgrp * 256 + lane15 * 16;

  i32x4 acc[8][4];
  {
    const i32x4 z = {0, 0, 0, 0};
#pragma unroll
    for (int i = 0; i < 8; ++i)
#pragma unroll
      for (int j2 = 0; j2 < 4; ++j2) acc[i][j2] = z;
  }
  i32x4 af[4][2], bfA[4][2], bfB[4][2];

  // ---- prologue: stage A(0), load B(0)->bfA, drain, sync ----
  STAGE_A(0, 0);
  LOADB(bfA, 0);
  TILE_GATE();

  for (int i = 0; i < NITER; ++i) {
    const int T1 = 2 * i + 1, T2 = 2 * i + 2;

    // ---- tile T0 = 2i (buf0, bfA); prefetch A(T1)->buf1, B(T1)->bfB ----
    STAGE_A(1, T1);
    LOADB(bfB, T1);
    COMPUTE(0, bfA);
    TILE_GATE();

    // ---- tile T1 (buf1, bfB); prefetch A(T2)->buf0, B(T2)->bfA ----
    if (i < NITER - 1) {
      STAGE_A(0, T2);
      LOADB(bfA, T2);
    }
    COMPUTE(1, bfB);
    TILE_GATE();
  }

  // ---- epilogue: C/D layout col=lane&15, row=(lane>>4)*4+reg; dequant ----
  const int ccol = bn * 256 + wn * 64 + lane15;
  const int crow0 = bm * 256 + wm * 128 + (lgrp << 2);
#pragma unroll
  for (int mi = 0; mi < 8; ++mi) {
#pragma unroll
    for (int j2 = 0; j2 < 4; ++j2) {
      const int row = crow0 + mi * 16 + j2;
      const float s = S[row];
      float* cp = C + (size_t)row * N_DIM + ccol;
#pragma unroll
      for (int ni = 0; ni < 4; ++ni) cp[ni * 16] = s * (float)acc[mi][ni][j2];
    }
  }
}

// Correctness fallback if d_ws is too small for the i8 staging buffers.
__global__ __launch_bounds__(256) void fallback_kernel(const float* __restrict__ x,
                                                       const float* __restrict__ w,
                                                       float* __restrict__ out) {
  const int col = blockIdx.x * 256 + threadIdx.x;
  const int row = blockIdx.y;
  const float* xr = x + (size_t)row * K_DIM;
  const float* wr = w + (size_t)col * K_DIM;
  float acc = 0.0f;
  for (int k = 0; k < K_DIM; k += 4) {
    float4 xv = *(const float4*)&xr[k];
    float4 wv = *(const float4*)&wr[k];
    acc += (wv.x > 0.0f ? xv.x : (wv.x < 0.0f ? -xv.x : 0.0f));
    acc += (wv.y > 0.0f ? xv.y : (wv.y < 0.0f ? -xv.y : 0.0f));
    acc += (wv.z > 0.0f ? xv.z : (wv.z < 0.0f ? -xv.z : 0.0f));
    acc += (wv.w > 0.0f ? xv.w : (wv.w < 0.0f ? -xv.w : 0.0f));
  }
  out[(size_t)row * N_DIM + col] = acc;
}

extern "C" void kernel_launch(void* const* d_in, const int* in_sizes, int n_in,
                              void* d_out, int out_size, void* d_ws, size_t ws_size,
                              hipStream_t stream) {
  const float* x = (const float*)d_in[0];  // (8192, 4096) fp32
  const float* w = (const float*)d_in[1];  // (4096, 4096) fp32
  float* out = (float*)d_out;              // (8192, 4096) fp32

  const size_t x_elems = (size_t)M_DIM * K_DIM;
  const size_t w_elems = (size_t)N_DIM * K_DIM;
  const size_t need = x_elems + w_elems + (size_t)M_DIM * sizeof(float);

  if (ws_size < need) {
    dim3 fgrid(N_DIM / 256, M_DIM);
    fallback_kernel<<<fgrid, 256, 0, stream>>>(x, w, out);
    return;
  }

  signed char* xq = (signed char*)d_ws;    // 32 MiB
  signed char* wq = xq + x_elems;          // 16 MiB, fragment-tiled
  float* scales = (float*)(wq + w_elems);  // 32 KiB

  cvt_x_i8<<<M_DIM, 256, 0, stream>>>(x, xq, scales);
  cvt_w_i8t<<<(N_DIM / 16) * (K_DIM / 256), 256, 0, stream>>>(w, wq);

  bingemm_kernel<<<(M_DIM / BM) * (N_DIM / BN), 512, 0, stream>>>(
      (const u8*)xq, (const u8*)wq, scales, out);
}